// Round 3
// baseline (543.536 us; speedup 1.0000x reference)
//
#include <hip/hip_runtime.h>

// AbstractLinear: y = x @ W.T + b  (256x8192x8192, bf16 MFMA)
//                 IBP bounds fused on W registers (fp32):
//                 P = W@(l+h), R = |W|@(h-l); low=.5(P-R)+b, high=.5(P+R)+b
// R7: cut A-side L2/L3 traffic. R6 post-mortem: dur tracked the 2 GB of
//     xpre re-reads through L2/L3 (~10.6 TB/s), not HBM. Changes:
//     (a) Nwave 16->32 (2 B-frags/wave) halves A bytes per MFMA;
//     (b) k-split 8 (not 4) x no n-wave pair -> no duplicate A reads.
//     Wave = M256 x N32 x k1024 (32 steps). A re-reads 2 GB -> 1 GB.
//     Grid 256 x 512thr, W still read-exactly-once linear streams.
//     Cross-kh y-reduction via LDS (8 rounds); bounds via pbuf/rbuf.
#define M_TOTAL 256
#define N_TOTAL 8192
#define K_TOTAL 8192

typedef __attribute__((ext_vector_type(4))) float f32x4;
typedef __attribute__((ext_vector_type(8))) short s16x8;
typedef __attribute__((ext_vector_type(4))) int   i32x4;
typedef unsigned short ushort_t;

// pack two fp32 -> two bf16 (truncation) in one v_perm_b32 (low = a, high = b)
__device__ __forceinline__ int pk(float a, float b) {
    return (int)__builtin_amdgcn_perm(__float_as_uint(b), __float_as_uint(a), 0x07060302u);
}

// ---------------- prep: x fp32 -> bf16 fragment-ordered; lh/hl precompute ----
// xpre chunk layout: ushort addr = (gk/8)*2048 + m*8 holds bf16(x[m][gk..gk+8])
// i.e. chunk id = (kt*8 + c)*256 + row, 16 B per chunk (verified R6).
__global__ __launch_bounds__(256)
void prep_kernel(const float* __restrict__ x,
                 const float* __restrict__ low,
                 const float* __restrict__ high,
                 ushort_t* __restrict__ xpre,
                 float* __restrict__ lh,
                 float* __restrict__ hl) {
    const int bx = blockIdx.x, t = threadIdx.x;
    if (bx < 1024) {
        const int id  = bx * 256 + t;   // 262144 chunks
        const int kt  = id >> 11;
        const int c   = (id >> 8) & 7;
        const int row = id & 255;
        const float* src = x + (size_t)row * K_TOTAL + kt * 64 + c * 8;
        f32x4 s0 = *(const f32x4*)(src);
        f32x4 s1 = *(const f32x4*)(src + 4);
        i32x4 bi;
        bi[0] = pk(s0[0], s0[1]); bi[1] = pk(s0[2], s0[3]);
        bi[2] = pk(s1[0], s1[1]); bi[3] = pk(s1[2], s1[3]);
        *(i32x4*)(xpre + (size_t)id * 8) = bi;
    } else {
        const int i = (bx - 1024) * 256 + t;   // 32 blocks x 256 = 8192
        float lo = low[i], hi = high[i];
        lh[i] = lo + hi;
        hl[i] = hi - lo;
    }
}

// ---------------- main ----------------
// 256 blocks x 512 thr = 8 waves; wave kh owns W rows [n0, n0+32) x
// k in [kh*1024, (kh+1)*1024), streamed sequentially (read-once).
__global__ __launch_bounds__(512, 2)
void abstract_linear_kernel(const ushort_t* __restrict__ xpre,
                            const float* __restrict__ W,
                            const float* __restrict__ lh,
                            const float* __restrict__ hl,
                            const float* __restrict__ bias,
                            float* __restrict__ out) {
    __shared__ float ybuf[M_TOTAL * 32];   // 32 KB cross-kh y reduction
    __shared__ float pbuf[8 * 32];
    __shared__ float rbuf[8 * 32];

    const int t    = threadIdx.x;
    const int kh   = t >> 6;       // k-slice 0..7
    const int lane = t & 63;
    const int l15  = lane & 15;
    const int lq   = lane >> 4;
    const int n0   = blockIdx.x * 32;

    f32x4 acc[16][2];              // [mi][nf] : M=256 x N=32
#pragma unroll
    for (int i = 0; i < 16; ++i) {
        acc[i][0] = (f32x4){0.f, 0.f, 0.f, 0.f};
        acc[i][1] = (f32x4){0.f, 0.f, 0.f, 0.f};
    }

    float P0 = 0.f, P1 = 0.f, R0 = 0.f, R1 = 0.f;

    const float*    wp0 = W + (size_t)(n0 + l15) * K_TOTAL + kh * 1024 + lq * 8;
    const float*    wp1 = wp0 + (size_t)16 * K_TOTAL;
    const float*    lhp = lh + kh * 1024 + lq * 8;
    const float*    hlp = hl + kh * 1024 + lq * 8;
    const ushort_t* ap  = xpre + (size_t)(kh * 128 + lq) * 2048 + l15 * 8;

    // 2-slot W register pipeline (1 step lookahead covers HBM latency)
    f32x4 wreg[2][4];   // [slot][w0A,w0B,w1A,w1B]

    auto ldW = [&](int sl, int st) {
        wreg[sl][0] = *(const f32x4*)(wp0 + st * 32);
        wreg[sl][1] = *(const f32x4*)(wp0 + st * 32 + 4);
        wreg[sl][2] = *(const f32x4*)(wp1 + st * 32);
        wreg[sl][3] = *(const f32x4*)(wp1 + st * 32 + 4);
    };

    auto compute = [&](int sl, int st) {
        f32x4 w0A = wreg[sl][0], w0B = wreg[sl][1];
        f32x4 w1A = wreg[sl][2], w1B = wreg[sl][3];
        i32x4 b0, b1;
        b0[0] = pk(w0A[0], w0A[1]); b0[1] = pk(w0A[2], w0A[3]);
        b0[2] = pk(w0B[0], w0B[1]); b0[3] = pk(w0B[2], w0B[3]);
        b1[0] = pk(w1A[0], w1A[1]); b1[1] = pk(w1A[2], w1A[3]);
        b1[2] = pk(w1B[0], w1B[1]); b1[3] = pk(w1B[2], w1B[3]);
        s16x8 bf0 = *(s16x8*)&b0;
        s16x8 bf1 = *(s16x8*)&b1;
        // lh/hl just-in-time: 4 KB per kh-slice, L1-resident
        f32x4 lA = *(const f32x4*)(lhp + st * 32);
        f32x4 lB = *(const f32x4*)(lhp + st * 32 + 4);
        f32x4 hA = *(const f32x4*)(hlp + st * 32);
        f32x4 hB = *(const f32x4*)(hlp + st * 32 + 4);
#pragma unroll
        for (int e = 0; e < 4; ++e) {
            P0 = fmaf(w0A[e], lA[e], P0); P0 = fmaf(w0B[e], lB[e], P0);
            R0 = fmaf(fabsf(w0A[e]), hA[e], R0); R0 = fmaf(fabsf(w0B[e]), hB[e], R0);
            P1 = fmaf(w1A[e], lA[e], P1); P1 = fmaf(w1B[e], lB[e], P1);
            R1 = fmaf(fabsf(w1A[e]), hA[e], R1); R1 = fmaf(fabsf(w1B[e]), hB[e], R1);
        }
        const ushort_t* a_st = ap + (size_t)st * 8192;
#pragma unroll
        for (int half = 0; half < 2; ++half) {
            s16x8 af[8];
#pragma unroll
            for (int mi = 0; mi < 8; ++mi)
                af[mi] = *(const s16x8*)(a_st + (half * 8 + mi) * 128);
#pragma unroll
            for (int mi = 0; mi < 8; ++mi) {
                acc[half * 8 + mi][0] = __builtin_amdgcn_mfma_f32_16x16x32_bf16(
                    af[mi], bf0, acc[half * 8 + mi][0], 0, 0, 0);
                acc[half * 8 + mi][1] = __builtin_amdgcn_mfma_f32_16x16x32_bf16(
                    af[mi], bf1, acc[half * 8 + mi][1], 0, 0, 0);
            }
        }
    };

    // 32 k32-steps per wave, no barriers, W stream purely sequential
    ldW(0, 0);
    for (int st = 0; st < 32; st += 2) {
        ldW(1, st + 1);
        compute(0, st);
        if (st < 30) ldW(0, st + 2);
        compute(1, st + 1);
    }

    // ---- bounds partials: reduce over the 4 lq lanes holding the same row ----
    P0 += __shfl_xor(P0, 16); P0 += __shfl_xor(P0, 32);
    P1 += __shfl_xor(P1, 16); P1 += __shfl_xor(P1, 32);
    R0 += __shfl_xor(R0, 16); R0 += __shfl_xor(R0, 32);
    R1 += __shfl_xor(R1, 16); R1 += __shfl_xor(R1, 32);
    if (lane < 16) {
        pbuf[kh * 32 + l15]      = P0;
        pbuf[kh * 32 + 16 + l15] = P1;
        rbuf[kh * 32 + l15]      = R0;
        rbuf[kh * 32 + 16 + l15] = R1;
    }

    const float bv0 = bias[n0 + l15];
    const float bv1 = bias[n0 + 16 + l15];

    // ---- y: cross-kh reduction through LDS, 8 serial rounds ----
    // C/D layout: col = lane&15 -> n, row = lq*4 + reg -> m (verified R6)
    for (int rr = 0; rr < 8; ++rr) {
        __syncthreads();
        if (kh == rr) {
#pragma unroll
            for (int mi = 0; mi < 16; ++mi) {
#pragma unroll
                for (int e = 0; e < 4; ++e) {
                    int m  = mi * 16 + lq * 4 + e;
                    int i0 = m * 32 + l15;
                    float v0 = acc[mi][0][e];
                    float v1 = acc[mi][1][e];
                    if (rr > 0) { v0 += ybuf[i0]; v1 += ybuf[i0 + 16]; }
                    if (rr < 7) { ybuf[i0] = v0; ybuf[i0 + 16] = v1; }
                    else {
                        out[(size_t)m * N_TOTAL + n0 + l15]      = v0 + bv0;
                        out[(size_t)m * N_TOTAL + n0 + 16 + l15] = v1 + bv1;
                    }
                }
            }
        }
    }
    __syncthreads();

    // ---- bounds epilogue: sum the 8 k-slices ----
    if (t < 32) {
        float Ps = 0.f, Rs = 0.f;
#pragma unroll
        for (int k = 0; k < 8; ++k) {
            Ps += pbuf[k * 32 + t];
            Rs += rbuf[k * 32 + t];
        }
        float bb = bias[n0 + t];
        out[(size_t)M_TOTAL * N_TOTAL + n0 + t]           = 0.5f * (Ps - Rs) + bb;
        out[(size_t)M_TOTAL * N_TOTAL + N_TOTAL + n0 + t] = 0.5f * (Ps + Rs) + bb;
    }
}

extern "C" void kernel_launch(void* const* d_in, const int* in_sizes, int n_in,
                              void* d_out, int out_size, void* d_ws, size_t ws_size,
                              hipStream_t stream) {
    const float* x    = (const float*)d_in[0];
    const float* low  = (const float*)d_in[1];
    const float* high = (const float*)d_in[2];
    const float* W    = (const float*)d_in[3];
    const float* b    = (const float*)d_in[4];
    float* out = (float*)d_out;

    // workspace: xpre 4 MB (bf16 fragment-ordered x) + lh 32 KB + hl 32 KB
    ushort_t* xpre = (ushort_t*)d_ws;
    float* lh = (float*)((char*)d_ws + (size_t)M_TOTAL * K_TOTAL * 2);
    float* hl = lh + K_TOTAL;

    hipLaunchKernelGGL(prep_kernel, dim3(1056), dim3(256), 0, stream,
                       x, low, high, xpre, lh, hl);
    hipLaunchKernelGGL(abstract_linear_kernel, dim3(N_TOTAL / 32), dim3(512), 0, stream,
                       xpre, W, lh, hl, b, out);
}